// Round 10
// baseline (664.275 us; speedup 1.0000x reference)
//
#include <hip/hip_runtime.h>
#include <math.h>

#define HID 128
#define HEADS 4
#define NEG_SLOPE 0.2f

typedef float f32x4 __attribute__((ext_vector_type(4)));
typedef _Float16 f16x8 __attribute__((ext_vector_type(8)));
typedef _Float16 f16x4 __attribute__((ext_vector_type(4)));
typedef _Float16 f16x2 __attribute__((ext_vector_type(2)));

#if defined(__has_builtin)
#if __has_builtin(__builtin_amdgcn_fdot2)
#define HAVE_FDOT2 1
#endif
#endif

// ---------------- CSR build ----------------

__global__ __launch_bounds__(256) void k_zero_int(int* p, int n) {
    int i = blockIdx.x * blockDim.x + threadIdx.x;
    if (i < n) p[i] = 0;
}

__global__ __launch_bounds__(256) void k_hist(const int* __restrict__ dst, int E, int* __restrict__ counts) {
    int e = blockIdx.x * blockDim.x + threadIdx.x;
    if (e < E) atomicAdd(&counts[dst[e]], 1);
}

__global__ __launch_bounds__(256) void k_scan_block(const int* __restrict__ counts, int N,
                                                    int* __restrict__ scanout, int* __restrict__ partials) {
    __shared__ int buf[256];
    int tid = threadIdx.x;
    int i = blockIdx.x * 256 + tid;
    int v = (i < N) ? counts[i] : 0;
    buf[tid] = v;
    __syncthreads();
    for (int off = 1; off < 256; off <<= 1) {
        int t = (tid >= off) ? buf[tid - off] : 0;
        __syncthreads();
        buf[tid] += t;
        __syncthreads();
    }
    if (i < N) scanout[i] = buf[tid] - v;
    if (tid == 255) partials[blockIdx.x] = buf[255];
}

__global__ __launch_bounds__(256) void k_scan_part(int* __restrict__ partials, int nb) {
    __shared__ int buf[256];
    int tid = threadIdx.x;
    int v = (tid < nb) ? partials[tid] : 0;
    buf[tid] = v;
    __syncthreads();
    for (int off = 1; off < 256; off <<= 1) {
        int t = (tid >= off) ? buf[tid - off] : 0;
        __syncthreads();
        buf[tid] += t;
        __syncthreads();
    }
    if (tid < nb) partials[tid] = buf[tid] - v;
}

__global__ __launch_bounds__(256) void k_scan_add(const int* __restrict__ scanout, const int* __restrict__ partials,
                                                  int N, int E, int* __restrict__ rowptr, int* __restrict__ nextp) {
    int i = blockIdx.x * 256 + threadIdx.x;
    if (i < N) {
        int r = scanout[i] + partials[blockIdx.x];
        rowptr[i] = r;
        nextp[i] = r;
    }
    if (i == 0) rowptr[N] = E;
}

// stores BYTE offsets (src * HID * 2) so the attn hot loop does base+off only
__global__ __launch_bounds__(256) void k_scatter(const int* __restrict__ src, const int* __restrict__ dst, int E,
                                                 int* __restrict__ nextp, int* __restrict__ csr_off) {
    int e = blockIdx.x * blockDim.x + threadIdx.x;
    if (e < E) {
        int d = dst[e];
        int pos = atomicAdd(&nextp[d], 1);
        csr_off[pos] = src[e] * (HID * 2);
    }
}

// ---------------- helpers ----------------

__device__ inline f16x2 absh2(f16x2 v) {
    unsigned u = __builtin_bit_cast(unsigned, v) & 0x7FFF7FFFu;
    return __builtin_bit_cast(f16x2, u);
}

// fp32 -> fp16 convert (for W, twice per launch, small)
__global__ __launch_bounds__(256) void k_tof16(const float* __restrict__ x, _Float16* __restrict__ o, int n) {
    int i = blockIdx.x * 256 + threadIdx.x;
    int base = i * 4;
    if (base >= n) return;
    float4 v = *(const float4*)(x + base);
    f16x4 h = {(_Float16)v.x, (_Float16)v.y, (_Float16)v.z, (_Float16)v.w};
    *(f16x4*)(o + base) = h;
}

// ---------------- MFMA linear, LDS-resident fp16 W ----------------
// fp16 inputs, fp32 MFMA accumulate (rel err ~5e-4, inside the 0.02 budget).
// blockIdx.y: 0 -> xlh = x@Wl.T+bl ; 1 -> xrh = x@Wr.T+br (both fp16).
// Block = 512 threads (8 waves) = 128 nodes; W (32 KB fp16) staged in LDS
// with XOR-chunk swizzle (2-way bank aliasing = free, m136).
// A frag: A[m=lane&15][k=quad*8+j]; B frag: W row n=lane&15, k contiguous.
// C/D: col=lane&15, row=quad*4+reg  (verified m89 mapping).

__global__ __launch_bounds__(512) void k_linear_mfma(
        const _Float16* __restrict__ xh,
        const _Float16* __restrict__ WfL, const _Float16* __restrict__ WfR,
        const float* __restrict__ bl, const float* __restrict__ br,
        _Float16* __restrict__ xlh, _Float16* __restrict__ xrh, int N) {
    __shared__ _Float16 lds[16384];   // 32 KB: W fp16, swizzled
    const int t   = threadIdx.x;
    const int mat = blockIdx.y;
    const _Float16* W = mat ? WfR : WfL;

    // stage W: 2048 16-B chunks; chunk g = (row r = g>>4, chunk cc = g&15)
    for (int g = t; g < 2048; g += 512) {
        int r = g >> 4, cc = g & 15;
        int dsto = r * 128 + ((cc ^ (r & 7)) << 3);      // half units
        *(float4*)&lds[dsto] = *(const float4*)(W + g * 8);
    }
    __syncthreads();

    const int wave = t >> 6;
    const int lane = t & 63;
    const int l16  = lane & 15;
    const int quad = lane >> 4;
    const int n0   = blockIdx.x * 128 + wave * 16;

    int arow = n0 + l16;
    if (arow >= N) arow = N - 1;       // clamp loads; stores guarded below

    f32x4 acc[8];
    #pragma unroll
    for (int s = 0; s < 8; s++) acc[s] = (f32x4){0.f, 0.f, 0.f, 0.f};

    #pragma unroll
    for (int k0 = 0; k0 < HID; k0 += 32) {
        f16x8 a = *(const f16x8*)(xh + arow * HID + k0 + quad * 8);
        const int cc = (k0 >> 3) + quad;
        #pragma unroll
        for (int s = 0; s < 8; s++) {
            const int row = s * 16 + l16;
            const int off = row * 128 + ((cc ^ (l16 & 7)) << 3);
            f16x8 b = *(const f16x8*)&lds[off];
            acc[s] = __builtin_amdgcn_mfma_f32_16x16x32_f16(a, b, acc[s], 0, 0, 0);
        }
    }

    const float* bias = mat ? br : bl;
    _Float16* dst = mat ? xrh : xlh;
    #pragma unroll
    for (int s = 0; s < 8; s++) {
        int col = s * 16 + l16;
        float bv = bias[col];
        #pragma unroll
        for (int r = 0; r < 4; r++) {
            int node = n0 + quad * 4 + r;
            if (node < N) dst[(size_t)node * HID + col] = (_Float16)(acc[s][r] + bv);
        }
    }
}

// ---------------- Fused attention: wave per node, 4 edge streams ----------------
// Stream = 16 lanes, f16x8 (16 B) per lane -> one 256 B row per stream per
// iteration; ~deg/4 iterations. 4 concurrent gathers + depth-2 prefetch each
// + byte-offset indices. Head-dot: in-lane 8-ch dot then 2 shfl_xor.
// No max-subtraction (|logit| <~ 3 << 88). Residual = fp16 x of prev layer;
// epilogue writes next layer's fp16 x (ping-pong) or fp32 out (last layer).

__global__ __launch_bounds__(256) void k_attn(const _Float16* __restrict__ xlh, const _Float16* __restrict__ xrh,
                                              const int* __restrict__ rowptr, const int* __restrict__ csr_off,
                                              const float* __restrict__ att, const float* __restrict__ bias,
                                              const _Float16* __restrict__ xres, _Float16* __restrict__ outx,
                                              float* __restrict__ out,
                                              int add_res, int want_half, int N) {
    const int wave = threadIdx.x >> 6;
    const int lane = threadIdx.x & 63;
    const int strm = lane >> 4;          // edge stream 0..3
    const int l16  = lane & 15;          // channels [8*l16, 8*l16+8); head = l16>>2
    const int n = blockIdx.x * 4 + wave;
    if (n >= N) return;

    const float4 aA = *(const float4*)(att + 8 * l16);
    const float4 aB = *(const float4*)(att + 8 * l16 + 4);
    const f16x2 a0 = (f16x2){(_Float16)aA.x, (_Float16)aA.y};
    const f16x2 a1 = (f16x2){(_Float16)aA.z, (_Float16)aA.w};
    const f16x2 a2 = (f16x2){(_Float16)aB.x, (_Float16)aB.y};
    const f16x2 a3 = (f16x2){(_Float16)aB.z, (_Float16)aB.w};
    const f16x8 xrv = *(const f16x8*)(xrh + (size_t)n * HID + 8 * l16);
    const f16x2 xr0 = __builtin_shufflevector(xrv, xrv, 0, 1);
    const f16x2 xr1 = __builtin_shufflevector(xrv, xrv, 2, 3);
    const f16x2 xr2 = __builtin_shufflevector(xrv, xrv, 4, 5);
    const f16x2 xr3 = __builtin_shufflevector(xrv, xrv, 6, 7);
    const f16x2 k06 = (f16x2){(_Float16)0.6f, (_Float16)0.6f};
    const f16x2 k04 = (f16x2){(_Float16)0.4f, (_Float16)0.4f};
    const int s0 = rowptr[n], s1 = rowptr[n + 1];

    float den = 0.f;
    float acc[8];
    #pragma unroll
    for (int q = 0; q < 8; q++) acc[q] = 0.f;

    const char* xlb = (const char*)xlh + l16 * 16;  // lane's 16B slice within a row

    int j = s0 + strm;
    if (j < s1) {
        const int last = s1 - 1;
        f16x8 p0 = *(const f16x8*)(xlb + csr_off[min(j,     last)]);
        f16x8 p1 = *(const f16x8*)(xlb + csr_off[min(j + 4, last)]);
        int   o2 = csr_off[min(j + 8, last)];
        while (j < s1) {
            f16x8 cur = p0;
            p0 = p1;
            p1 = *(const f16x8*)(xlb + o2);
            o2 = csr_off[min(j + 12, last)];

            f16x2 c0 = __builtin_shufflevector(cur, cur, 0, 1);
            f16x2 c1 = __builtin_shufflevector(cur, cur, 2, 3);
            f16x2 c2 = __builtin_shufflevector(cur, cur, 4, 5);
            f16x2 c3 = __builtin_shufflevector(cur, cur, 6, 7);
            f16x2 u0 = c0 + xr0, u1 = c1 + xr1, u2 = c2 + xr2, u3 = c3 + xr3;
            f16x2 l0 = u0 * k06 + absh2(u0) * k04;   // leaky_relu, packed
            f16x2 l1 = u1 * k06 + absh2(u1) * k04;
            f16x2 l2 = u2 * k06 + absh2(u2) * k04;
            f16x2 l3 = u3 * k06 + absh2(u3) * k04;
#ifdef HAVE_FDOT2
            float p = __builtin_amdgcn_fdot2(l0, a0, 0.f, false);
            p = __builtin_amdgcn_fdot2(l1, a1, p, false);
            p = __builtin_amdgcn_fdot2(l2, a2, p, false);
            p = __builtin_amdgcn_fdot2(l3, a3, p, false);
#else
            float p = (float)l0[0] * (float)a0[0] + (float)l0[1] * (float)a0[1]
                    + (float)l1[0] * (float)a1[0] + (float)l1[1] * (float)a1[1]
                    + (float)l2[0] * (float)a2[0] + (float)l2[1] * (float)a2[1]
                    + (float)l3[0] * (float)a3[0] + (float)l3[1] * (float)a3[1];
#endif
            p += __shfl_xor(p, 1);           // reduce 4-lane head group
            p += __shfl_xor(p, 2);
            float w = __expf(p);
            den += w;
            #pragma unroll
            for (int q = 0; q < 8; q++) acc[q] += w * (float)cur[q];
            j += 4;
        }
    }

    // merge the four streams (lane stride 16/32)
    den += __shfl_xor(den, 16);
    den += __shfl_xor(den, 32);
    #pragma unroll
    for (int q = 0; q < 8; q++) {
        acc[q] += __shfl_xor(acc[q], 16);
        acc[q] += __shfl_xor(acc[q], 32);
    }

    if (strm == 0) {
        float4 bA = *(const float4*)(bias + 8 * l16);
        float4 bB = *(const float4*)(bias + 8 * l16 + 4);
        float b[8] = {bA.x, bA.y, bA.z, bA.w, bB.x, bB.y, bB.z, bB.w};
        float inv = (den > 0.f) ? 1.f / den : 0.f;
        float v[8];
        #pragma unroll
        for (int q = 0; q < 8; q++) v[q] = fmaxf(acc[q] * inv + b[q], 0.f);
        if (add_res) {
            f16x8 r = *(const f16x8*)(xres + (size_t)n * HID + 8 * l16);
            #pragma unroll
            for (int q = 0; q < 8; q++) v[q] += (float)r[q];
        }
        if (want_half) {
            f16x8 h;
            #pragma unroll
            for (int q = 0; q < 8; q++) h[q] = (_Float16)v[q];
            *(f16x8*)(outx + (size_t)n * HID + 8 * l16) = h;
        } else {
            *(float4*)(out + (size_t)n * HID + 8 * l16)     = make_float4(v[0], v[1], v[2], v[3]);
            *(float4*)(out + (size_t)n * HID + 8 * l16 + 4) = make_float4(v[4], v[5], v[6], v[7]);
        }
    }
}

// ---------------- Embedding: x = relu(nf @ W_emb.T + b_emb) -> fp16 ----------------

__global__ __launch_bounds__(128) void k_embed(const float* __restrict__ nf, const float* __restrict__ W,
                                               const float* __restrict__ b,
                                               _Float16* __restrict__ xh, int N) {
    __shared__ float f[11];
    int n = blockIdx.x;
    int h = threadIdx.x;
    if (h < 11) f[h] = nf[(size_t)n * 11 + h];
    __syncthreads();
    float acc = b[h];
    #pragma unroll
    for (int k = 0; k < 11; k++) acc += f[k] * W[h * 11 + k];
    xh[(size_t)n * HID + h] = (_Float16)fmaxf(acc, 0.f);
}

// ---------------- Graph readout: mean + max over nodes ----------------
// reduce1: 64 partial blocks. reduce2: 1024 threads (8 chunks x 128 ch) + LDS tree.

__global__ __launch_bounds__(128) void k_reduce1(const float* __restrict__ x, int N,
                                                 float* __restrict__ psum, float* __restrict__ pmax) {
    int b = blockIdx.x;
    int h = threadIdx.x;
    int per = (N + gridDim.x - 1) / gridDim.x;
    int n0 = b * per, n1 = min(N, n0 + per);
    float s = 0.f, m = -INFINITY;
    for (int n = n0; n < n1; n++) {
        float v = x[(size_t)n * HID + h];
        s += v;
        m = fmaxf(m, v);
    }
    psum[b * HID + h] = s;
    pmax[b * HID + h] = m;
}

__global__ __launch_bounds__(1024) void k_reduce2(const float* __restrict__ psum, const float* __restrict__ pmax,
                                                  int nb, float* __restrict__ out, float invN) {
    __shared__ float ss[8][HID];
    __shared__ float sm[8][HID];
    int h = threadIdx.x & 127;
    int c = threadIdx.x >> 7;          // chunk 0..7
    int per = nb >> 3;                 // nb = 64 -> 8 each
    float s = 0.f, m = -INFINITY;
    for (int b = c * per; b < (c + 1) * per; b++) {
        s += psum[b * HID + h];
        m = fmaxf(m, pmax[b * HID + h]);
    }
    ss[c][h] = s; sm[c][h] = m;
    __syncthreads();
    if (c < 4) { ss[c][h] += ss[c + 4][h]; sm[c][h] = fmaxf(sm[c][h], sm[c + 4][h]); }
    __syncthreads();
    if (c < 2) { ss[c][h] += ss[c + 2][h]; sm[c][h] = fmaxf(sm[c][h], sm[c + 2][h]); }
    __syncthreads();
    if (c == 0) {
        out[h] = (ss[0][h] + ss[1][h]) * invN;
        out[HID + h] = fmaxf(sm[0][h], sm[1][h]);
    }
}

// ---------------- Launch ----------------

extern "C" void kernel_launch(void* const* d_in, const int* in_sizes, int n_in,
                              void* d_out, int out_size, void* d_ws, size_t ws_size,
                              hipStream_t stream) {
    const float* nf    = (const float*)d_in[0];
    const int*   ei    = (const int*)d_in[1];
    const float* W_emb = (const float*)d_in[3];
    const float* b_emb = (const float*)d_in[4];
    const float* Wl    = (const float*)d_in[5];
    const float* bl    = (const float*)d_in[6];
    const float* Wr    = (const float*)d_in[7];
    const float* br    = (const float*)d_in[8];
    const float* att   = (const float*)d_in[9];
    const float* bias  = (const float*)d_in[10];

    const int N = in_sizes[0] / 11;
    const int E = in_sizes[1] / 2;
    const int* src = ei;
    const int* dst = ei + E;

    float* out  = (float*)d_out;
    float* xout = out + 2 * HID;

    // workspace carve-up
    char* w = (char*)d_ws;
    _Float16* xlh  = (_Float16*)w; w += (size_t)N * HID * 2;
    _Float16* xrh  = (_Float16*)w; w += (size_t)N * HID * 2;
    _Float16* xA   = (_Float16*)w; w += (size_t)N * HID * 2;
    _Float16* xB   = (_Float16*)w; w += (size_t)N * HID * 2;
    _Float16* WfL  = (_Float16*)w; w += (size_t)4 * HID * HID * 2;
    _Float16* WfR  = (_Float16*)w; w += (size_t)4 * HID * HID * 2;
    int*   counts   = (int*)w;   w += (size_t)N * 4;
    int*   scanout  = (int*)w;   w += (size_t)N * 4;
    int*   rowptr   = (int*)w;   w += (size_t)(N + 1) * 4;
    int*   nextp    = (int*)w;   w += (size_t)N * 4;
    int*   partials = (int*)w;   w += (size_t)256 * 4;
    int*   csr_off  = (int*)w;   w += (size_t)E * 4;
    float* psum     = (float*)w; w += (size_t)64 * HID * 4;
    float* pmax     = (float*)w; w += (size_t)64 * HID * 4;

    const int nb = (N + 255) / 256;
    const int nW = 4 * HID * HID;

    // weight fp16 conversion (once per launch)
    k_tof16<<<(nW / 4 + 255) / 256, 256, 0, stream>>>(Wl, WfL, nW);
    k_tof16<<<(nW / 4 + 255) / 256, 256, 0, stream>>>(Wr, WfR, nW);

    // CSR build
    k_zero_int<<<nb, 256, 0, stream>>>(counts, N);
    k_hist<<<(E + 255) / 256, 256, 0, stream>>>(dst, E, counts);
    k_scan_block<<<nb, 256, 0, stream>>>(counts, N, scanout, partials);
    k_scan_part<<<1, 256, 0, stream>>>(partials, nb);
    k_scan_add<<<nb, 256, 0, stream>>>(scanout, partials, N, E, rowptr, nextp);
    k_scatter<<<(E + 255) / 256, 256, 0, stream>>>(src, dst, E, nextp, csr_off);

    // embedding -> fp16 x (buffer A)
    k_embed<<<N, 128, 0, stream>>>(nf, W_emb, b_emb, xA, N);

    dim3 lgrid((N + 127) / 128, 2);
    for (int i = 0; i < 4; i++) {
        // ping-pong: even layers read A write B, odd layers read B write A
        const _Float16* xin = (i & 1) ? xB : xA;
        _Float16* xo        = (i & 1) ? xA : xB;
        k_linear_mfma<<<lgrid, 512, 0, stream>>>(xin,
                                                 WfL + (size_t)i * HID * HID, WfR + (size_t)i * HID * HID,
                                                 bl + i * HID, br + i * HID, xlh, xrh, N);
        k_attn<<<(N + 3) / 4, 256, 0, stream>>>(xlh, xrh, rowptr, csr_off,
                                                att + i * HEADS * 32, bias + i * HID,
                                                xin, xo, xout,
                                                i > 0 ? 1 : 0, i < 3 ? 1 : 0, N);
    }

    k_reduce1<<<64, 128, 0, stream>>>(xout, N, psum, pmax);
    k_reduce2<<<1, 1024, 0, stream>>>(psum, pmax, 64, out, 1.0f / N);
}

// Round 11
// 500.597 us; speedup vs baseline: 1.3270x; 1.3270x over previous
//
#include <hip/hip_runtime.h>
#include <math.h>

#define HID 128
#define HEADS 4
#define NEG_SLOPE 0.2f
#define R1B 1024   // reduce1 grid

typedef float f32x4 __attribute__((ext_vector_type(4)));
typedef _Float16 f16x8 __attribute__((ext_vector_type(8)));
typedef _Float16 f16x4 __attribute__((ext_vector_type(4)));
typedef _Float16 f16x2 __attribute__((ext_vector_type(2)));

#if defined(__has_builtin)
#if __has_builtin(__builtin_amdgcn_fdot2)
#define HAVE_FDOT2 1
#endif
#endif

// ---------------- CSR build ----------------

__global__ __launch_bounds__(256) void k_zero_int(int* p, int n) {
    int i = blockIdx.x * blockDim.x + threadIdx.x;
    if (i < n) p[i] = 0;
}

__global__ __launch_bounds__(256) void k_hist(const int* __restrict__ dst, int E, int* __restrict__ counts) {
    int e = blockIdx.x * blockDim.x + threadIdx.x;
    if (e < E) atomicAdd(&counts[dst[e]], 1);
}

__global__ __launch_bounds__(256) void k_scan_block(const int* __restrict__ counts, int N,
                                                    int* __restrict__ scanout, int* __restrict__ partials) {
    __shared__ int buf[256];
    int tid = threadIdx.x;
    int i = blockIdx.x * 256 + tid;
    int v = (i < N) ? counts[i] : 0;
    buf[tid] = v;
    __syncthreads();
    for (int off = 1; off < 256; off <<= 1) {
        int t = (tid >= off) ? buf[tid - off] : 0;
        __syncthreads();
        buf[tid] += t;
        __syncthreads();
    }
    if (i < N) scanout[i] = buf[tid] - v;
    if (tid == 255) partials[blockIdx.x] = buf[255];
}

__global__ __launch_bounds__(256) void k_scan_part(int* __restrict__ partials, int nb) {
    __shared__ int buf[256];
    int tid = threadIdx.x;
    int v = (tid < nb) ? partials[tid] : 0;
    buf[tid] = v;
    __syncthreads();
    for (int off = 1; off < 256; off <<= 1) {
        int t = (tid >= off) ? buf[tid - off] : 0;
        __syncthreads();
        buf[tid] += t;
        __syncthreads();
    }
    if (tid < nb) partials[tid] = buf[tid] - v;
}

__global__ __launch_bounds__(256) void k_scan_add(const int* __restrict__ scanout, const int* __restrict__ partials,
                                                  int N, int E, int* __restrict__ rowptr, int* __restrict__ nextp) {
    int i = blockIdx.x * 256 + threadIdx.x;
    if (i < N) {
        int r = scanout[i] + partials[blockIdx.x];
        rowptr[i] = r;
        nextp[i] = r;
    }
    if (i == 0) rowptr[N] = E;
}

// stores BYTE offsets (src * HID * 2) so the attn hot loop does base+off only
__global__ __launch_bounds__(256) void k_scatter(const int* __restrict__ src, const int* __restrict__ dst, int E,
                                                 int* __restrict__ nextp, int* __restrict__ csr_off) {
    int e = blockIdx.x * blockDim.x + threadIdx.x;
    if (e < E) {
        int d = dst[e];
        int pos = atomicAdd(&nextp[d], 1);
        csr_off[pos] = src[e] * (HID * 2);
    }
}

// ---------------- helpers ----------------

__device__ inline f16x2 absh2(f16x2 v) {
    unsigned u = __builtin_bit_cast(unsigned, v) & 0x7FFF7FFFu;
    return __builtin_bit_cast(f16x2, u);
}

// fp32 -> fp16 convert (for W, twice per launch, small)
__global__ __launch_bounds__(256) void k_tof16(const float* __restrict__ x, _Float16* __restrict__ o, int n) {
    int i = blockIdx.x * 256 + threadIdx.x;
    int base = i * 4;
    if (base >= n) return;
    float4 v = *(const float4*)(x + base);
    f16x4 h = {(_Float16)v.x, (_Float16)v.y, (_Float16)v.z, (_Float16)v.w};
    *(f16x4*)(o + base) = h;
}

// ---------------- MFMA linear, LDS-resident fp16 W ----------------
// fp16 inputs, fp32 MFMA accumulate (rel err ~5e-4, inside the 0.02 budget).
// blockIdx.y: 0 -> xlh = x@Wl.T+bl ; 1 -> xrh = x@Wr.T+br (both fp16).
// Block = 512 threads (8 waves) = 128 nodes; W (32 KB fp16) staged in LDS
// with XOR-chunk swizzle (2-way bank aliasing = free, m136).

__global__ __launch_bounds__(512) void k_linear_mfma(
        const _Float16* __restrict__ xh,
        const _Float16* __restrict__ WfL, const _Float16* __restrict__ WfR,
        const float* __restrict__ bl, const float* __restrict__ br,
        _Float16* __restrict__ xlh, _Float16* __restrict__ xrh, int N) {
    __shared__ _Float16 lds[16384];   // 32 KB: W fp16, swizzled
    const int t   = threadIdx.x;
    const int mat = blockIdx.y;
    const _Float16* W = mat ? WfR : WfL;

    for (int g = t; g < 2048; g += 512) {
        int r = g >> 4, cc = g & 15;
        int dsto = r * 128 + ((cc ^ (r & 7)) << 3);      // half units
        *(float4*)&lds[dsto] = *(const float4*)(W + g * 8);
    }
    __syncthreads();

    const int wave = t >> 6;
    const int lane = t & 63;
    const int l16  = lane & 15;
    const int quad = lane >> 4;
    const int n0   = blockIdx.x * 128 + wave * 16;

    int arow = n0 + l16;
    if (arow >= N) arow = N - 1;       // clamp loads; stores guarded below

    f32x4 acc[8];
    #pragma unroll
    for (int s = 0; s < 8; s++) acc[s] = (f32x4){0.f, 0.f, 0.f, 0.f};

    #pragma unroll
    for (int k0 = 0; k0 < HID; k0 += 32) {
        f16x8 a = *(const f16x8*)(xh + arow * HID + k0 + quad * 8);
        const int cc = (k0 >> 3) + quad;
        #pragma unroll
        for (int s = 0; s < 8; s++) {
            const int row = s * 16 + l16;
            const int off = row * 128 + ((cc ^ (l16 & 7)) << 3);
            f16x8 b = *(const f16x8*)&lds[off];
            acc[s] = __builtin_amdgcn_mfma_f32_16x16x32_f16(a, b, acc[s], 0, 0, 0);
        }
    }

    const float* bias = mat ? br : bl;
    _Float16* dst = mat ? xrh : xlh;
    #pragma unroll
    for (int s = 0; s < 8; s++) {
        int col = s * 16 + l16;
        float bv = bias[col];
        #pragma unroll
        for (int r = 0; r < 4; r++) {
            int node = n0 + quad * 4 + r;
            if (node < N) dst[(size_t)node * HID + col] = (_Float16)(acc[s][r] + bv);
        }
    }
}

// ---------------- Fused attention: wave per node, 4 edge streams ----------------

__global__ __launch_bounds__(256) void k_attn(const _Float16* __restrict__ xlh, const _Float16* __restrict__ xrh,
                                              const int* __restrict__ rowptr, const int* __restrict__ csr_off,
                                              const float* __restrict__ att, const float* __restrict__ bias,
                                              const _Float16* __restrict__ xres, _Float16* __restrict__ outx,
                                              float* __restrict__ out,
                                              int add_res, int want_half, int N) {
    const int wave = threadIdx.x >> 6;
    const int lane = threadIdx.x & 63;
    const int strm = lane >> 4;          // edge stream 0..3
    const int l16  = lane & 15;          // channels [8*l16, 8*l16+8); head = l16>>2
    const int n = blockIdx.x * 4 + wave;
    if (n >= N) return;

    const float4 aA = *(const float4*)(att + 8 * l16);
    const float4 aB = *(const float4*)(att + 8 * l16 + 4);
    const f16x2 a0 = (f16x2){(_Float16)aA.x, (_Float16)aA.y};
    const f16x2 a1 = (f16x2){(_Float16)aA.z, (_Float16)aA.w};
    const f16x2 a2 = (f16x2){(_Float16)aB.x, (_Float16)aB.y};
    const f16x2 a3 = (f16x2){(_Float16)aB.z, (_Float16)aB.w};
    const f16x8 xrv = *(const f16x8*)(xrh + (size_t)n * HID + 8 * l16);
    const f16x2 xr0 = __builtin_shufflevector(xrv, xrv, 0, 1);
    const f16x2 xr1 = __builtin_shufflevector(xrv, xrv, 2, 3);
    const f16x2 xr2 = __builtin_shufflevector(xrv, xrv, 4, 5);
    const f16x2 xr3 = __builtin_shufflevector(xrv, xrv, 6, 7);
    const f16x2 k06 = (f16x2){(_Float16)0.6f, (_Float16)0.6f};
    const f16x2 k04 = (f16x2){(_Float16)0.4f, (_Float16)0.4f};
    const int s0 = rowptr[n], s1 = rowptr[n + 1];

    float den = 0.f;
    float acc[8];
    #pragma unroll
    for (int q = 0; q < 8; q++) acc[q] = 0.f;

    const char* xlb = (const char*)xlh + l16 * 16;  // lane's 16B slice within a row

    int j = s0 + strm;
    if (j < s1) {
        const int last = s1 - 1;
        f16x8 p0 = *(const f16x8*)(xlb + csr_off[min(j,     last)]);
        f16x8 p1 = *(const f16x8*)(xlb + csr_off[min(j + 4, last)]);
        int   o2 = csr_off[min(j + 8, last)];
        while (j < s1) {
            f16x8 cur = p0;
            p0 = p1;
            p1 = *(const f16x8*)(xlb + o2);
            o2 = csr_off[min(j + 12, last)];

            f16x2 c0 = __builtin_shufflevector(cur, cur, 0, 1);
            f16x2 c1 = __builtin_shufflevector(cur, cur, 2, 3);
            f16x2 c2 = __builtin_shufflevector(cur, cur, 4, 5);
            f16x2 c3 = __builtin_shufflevector(cur, cur, 6, 7);
            f16x2 u0 = c0 + xr0, u1 = c1 + xr1, u2 = c2 + xr2, u3 = c3 + xr3;
            f16x2 l0 = u0 * k06 + absh2(u0) * k04;   // leaky_relu, packed
            f16x2 l1 = u1 * k06 + absh2(u1) * k04;
            f16x2 l2 = u2 * k06 + absh2(u2) * k04;
            f16x2 l3 = u3 * k06 + absh2(u3) * k04;
#ifdef HAVE_FDOT2
            float p = __builtin_amdgcn_fdot2(l0, a0, 0.f, false);
            p = __builtin_amdgcn_fdot2(l1, a1, p, false);
            p = __builtin_amdgcn_fdot2(l2, a2, p, false);
            p = __builtin_amdgcn_fdot2(l3, a3, p, false);
#else
            float p = (float)l0[0] * (float)a0[0] + (float)l0[1] * (float)a0[1]
                    + (float)l1[0] * (float)a1[0] + (float)l1[1] * (float)a1[1]
                    + (float)l2[0] * (float)a2[0] + (float)l2[1] * (float)a2[1]
                    + (float)l3[0] * (float)a3[0] + (float)l3[1] * (float)a3[1];
#endif
            p += __shfl_xor(p, 1);           // reduce 4-lane head group
            p += __shfl_xor(p, 2);
            float w = __expf(p);
            den += w;
            #pragma unroll
            for (int q = 0; q < 8; q++) acc[q] += w * (float)cur[q];
            j += 4;
        }
    }

    // merge the four streams (lane stride 16/32)
    den += __shfl_xor(den, 16);
    den += __shfl_xor(den, 32);
    #pragma unroll
    for (int q = 0; q < 8; q++) {
        acc[q] += __shfl_xor(acc[q], 16);
        acc[q] += __shfl_xor(acc[q], 32);
    }

    if (strm == 0) {
        float4 bA = *(const float4*)(bias + 8 * l16);
        float4 bB = *(const float4*)(bias + 8 * l16 + 4);
        float b[8] = {bA.x, bA.y, bA.z, bA.w, bB.x, bB.y, bB.z, bB.w};
        float inv = (den > 0.f) ? 1.f / den : 0.f;
        float v[8];
        #pragma unroll
        for (int q = 0; q < 8; q++) v[q] = fmaxf(acc[q] * inv + b[q], 0.f);
        if (add_res) {
            f16x8 r = *(const f16x8*)(xres + (size_t)n * HID + 8 * l16);
            #pragma unroll
            for (int q = 0; q < 8; q++) v[q] += (float)r[q];
        }
        if (want_half) {
            f16x8 h;
            #pragma unroll
            for (int q = 0; q < 8; q++) h[q] = (_Float16)v[q];
            *(f16x8*)(outx + (size_t)n * HID + 8 * l16) = h;
        } else {
            *(float4*)(out + (size_t)n * HID + 8 * l16)     = make_float4(v[0], v[1], v[2], v[3]);
            *(float4*)(out + (size_t)n * HID + 8 * l16 + 4) = make_float4(v[4], v[5], v[6], v[7]);
        }
    }
}

// ---------------- Embedding: x = relu(nf @ W_emb.T + b_emb) -> fp16 ----------------

__global__ __launch_bounds__(128) void k_embed(const float* __restrict__ nf, const float* __restrict__ W,
                                               const float* __restrict__ b,
                                               _Float16* __restrict__ xh, int N) {
    __shared__ float f[11];
    int n = blockIdx.x;
    int h = threadIdx.x;
    if (h < 11) f[h] = nf[(size_t)n * 11 + h];
    __syncthreads();
    float acc = b[h];
    #pragma unroll
    for (int k = 0; k < 11; k++) acc += f[k] * W[h * 11 + k];
    xh[(size_t)n * HID + h] = (_Float16)fmaxf(acc, 0.f);
}

// ---------------- Graph readout: mean + max over nodes ----------------
// reduce1: R1B blocks x 256 threads (8 row-lanes x 32 ch-lanes, float4);
// ~6 independent float4 loads per thread; LDS tree over row-lanes.
// reduce2: 1024 threads (8 chunks x 128 ch) over R1B partials + LDS tree.

__global__ __launch_bounds__(256) void k_reduce1(const float* __restrict__ x, int N,
                                                 float* __restrict__ psum, float* __restrict__ pmax) {
    __shared__ float ls[8][HID];
    __shared__ float lm[8][HID];
    const int c4 = (threadIdx.x & 31) << 2;   // channel base
    const int rl = threadIdx.x >> 5;          // row lane 0..7
    const int per = (N + gridDim.x - 1) / gridDim.x;
    const int n0 = blockIdx.x * per, n1 = min(N, n0 + per);
    float4 s = make_float4(0.f, 0.f, 0.f, 0.f);
    float4 m = make_float4(-INFINITY, -INFINITY, -INFINITY, -INFINITY);
    for (int n = n0 + rl; n < n1; n += 8) {
        float4 v = *(const float4*)(x + (size_t)n * HID + c4);
        s.x += v.x; s.y += v.y; s.z += v.z; s.w += v.w;
        m.x = fmaxf(m.x, v.x); m.y = fmaxf(m.y, v.y);
        m.z = fmaxf(m.z, v.z); m.w = fmaxf(m.w, v.w);
    }
    *(float4*)&ls[rl][c4] = s;
    *(float4*)&lm[rl][c4] = m;
    __syncthreads();
    if (rl < 4) {
        float4 a = *(float4*)&ls[rl][c4], bq = *(float4*)&ls[rl + 4][c4];
        a.x += bq.x; a.y += bq.y; a.z += bq.z; a.w += bq.w;
        *(float4*)&ls[rl][c4] = a;
        float4 am = *(float4*)&lm[rl][c4], bm = *(float4*)&lm[rl + 4][c4];
        am.x = fmaxf(am.x, bm.x); am.y = fmaxf(am.y, bm.y);
        am.z = fmaxf(am.z, bm.z); am.w = fmaxf(am.w, bm.w);
        *(float4*)&lm[rl][c4] = am;
    }
    __syncthreads();
    if (rl < 2) {
        float4 a = *(float4*)&ls[rl][c4], bq = *(float4*)&ls[rl + 2][c4];
        a.x += bq.x; a.y += bq.y; a.z += bq.z; a.w += bq.w;
        *(float4*)&ls[rl][c4] = a;
        float4 am = *(float4*)&lm[rl][c4], bm = *(float4*)&lm[rl + 2][c4];
        am.x = fmaxf(am.x, bm.x); am.y = fmaxf(am.y, bm.y);
        am.z = fmaxf(am.z, bm.z); am.w = fmaxf(am.w, bm.w);
        *(float4*)&lm[rl][c4] = am;
    }
    __syncthreads();
    if (rl == 0) {
        float4 a = *(float4*)&ls[0][c4], bq = *(float4*)&ls[1][c4];
        a.x += bq.x; a.y += bq.y; a.z += bq.z; a.w += bq.w;
        *(float4*)(psum + (size_t)blockIdx.x * HID + c4) = a;
        float4 am = *(float4*)&lm[0][c4], bm = *(float4*)&lm[1][c4];
        am.x = fmaxf(am.x, bm.x); am.y = fmaxf(am.y, bm.y);
        am.z = fmaxf(am.z, bm.z); am.w = fmaxf(am.w, bm.w);
        *(float4*)(pmax + (size_t)blockIdx.x * HID + c4) = am;
    }
}

__global__ __launch_bounds__(1024) void k_reduce2(const float* __restrict__ psum, const float* __restrict__ pmax,
                                                  int nb, float* __restrict__ out, float invN) {
    __shared__ float ss[8][HID];
    __shared__ float sm[8][HID];
    int h = threadIdx.x & 127;
    int c = threadIdx.x >> 7;          // chunk 0..7
    int per = nb >> 3;
    float s = 0.f, m = -INFINITY;
    for (int b = c * per; b < (c + 1) * per; b++) {
        s += psum[b * HID + h];
        m = fmaxf(m, pmax[b * HID + h]);
    }
    ss[c][h] = s; sm[c][h] = m;
    __syncthreads();
    if (c < 4) { ss[c][h] += ss[c + 4][h]; sm[c][h] = fmaxf(sm[c][h], sm[c + 4][h]); }
    __syncthreads();
    if (c < 2) { ss[c][h] += ss[c + 2][h]; sm[c][h] = fmaxf(sm[c][h], sm[c + 2][h]); }
    __syncthreads();
    if (c == 0) {
        out[h] = (ss[0][h] + ss[1][h]) * invN;
        out[HID + h] = fmaxf(sm[0][h], sm[1][h]);
    }
}

// ---------------- Launch ----------------

extern "C" void kernel_launch(void* const* d_in, const int* in_sizes, int n_in,
                              void* d_out, int out_size, void* d_ws, size_t ws_size,
                              hipStream_t stream) {
    const float* nf    = (const float*)d_in[0];
    const int*   ei    = (const int*)d_in[1];
    const float* W_emb = (const float*)d_in[3];
    const float* b_emb = (const float*)d_in[4];
    const float* Wl    = (const float*)d_in[5];
    const float* bl    = (const float*)d_in[6];
    const float* Wr    = (const float*)d_in[7];
    const float* br    = (const float*)d_in[8];
    const float* att   = (const float*)d_in[9];
    const float* bias  = (const float*)d_in[10];

    const int N = in_sizes[0] / 11;
    const int E = in_sizes[1] / 2;
    const int* src = ei;
    const int* dst = ei + E;

    float* out  = (float*)d_out;
    float* xout = out + 2 * HID;

    // workspace carve-up
    char* w = (char*)d_ws;
    _Float16* xlh  = (_Float16*)w; w += (size_t)N * HID * 2;
    _Float16* xrh  = (_Float16*)w; w += (size_t)N * HID * 2;
    _Float16* xA   = (_Float16*)w; w += (size_t)N * HID * 2;
    _Float16* xB   = (_Float16*)w; w += (size_t)N * HID * 2;
    _Float16* WfL  = (_Float16*)w; w += (size_t)4 * HID * HID * 2;
    _Float16* WfR  = (_Float16*)w; w += (size_t)4 * HID * HID * 2;
    int*   counts   = (int*)w;   w += (size_t)N * 4;
    int*   scanout  = (int*)w;   w += (size_t)N * 4;
    int*   rowptr   = (int*)w;   w += (size_t)(N + 1) * 4;
    int*   nextp    = (int*)w;   w += (size_t)N * 4;
    int*   partials = (int*)w;   w += (size_t)256 * 4;
    int*   csr_off  = (int*)w;   w += (size_t)E * 4;
    float* psum     = (float*)w; w += (size_t)R1B * HID * 4;
    float* pmax     = (float*)w; w += (size_t)R1B * HID * 4;

    const int nb = (N + 255) / 256;
    const int nW = 4 * HID * HID;

    // weight fp16 conversion (once per launch)
    k_tof16<<<(nW / 4 + 255) / 256, 256, 0, stream>>>(Wl, WfL, nW);
    k_tof16<<<(nW / 4 + 255) / 256, 256, 0, stream>>>(Wr, WfR, nW);

    // CSR build
    k_zero_int<<<nb, 256, 0, stream>>>(counts, N);
    k_hist<<<(E + 255) / 256, 256, 0, stream>>>(dst, E, counts);
    k_scan_block<<<nb, 256, 0, stream>>>(counts, N, scanout, partials);
    k_scan_part<<<1, 256, 0, stream>>>(partials, nb);
    k_scan_add<<<nb, 256, 0, stream>>>(scanout, partials, N, E, rowptr, nextp);
    k_scatter<<<(E + 255) / 256, 256, 0, stream>>>(src, dst, E, nextp, csr_off);

    // embedding -> fp16 x (buffer A)
    k_embed<<<N, 128, 0, stream>>>(nf, W_emb, b_emb, xA, N);

    dim3 lgrid((N + 127) / 128, 2);
    for (int i = 0; i < 4; i++) {
        // ping-pong: even layers read A write B, odd layers read B write A
        const _Float16* xin = (i & 1) ? xB : xA;
        _Float16* xo        = (i & 1) ? xA : xB;
        k_linear_mfma<<<lgrid, 512, 0, stream>>>(xin,
                                                 WfL + (size_t)i * HID * HID, WfR + (size_t)i * HID * HID,
                                                 bl + i * HID, br + i * HID, xlh, xrh, N);
        k_attn<<<(N + 3) / 4, 256, 0, stream>>>(xlh, xrh, rowptr, csr_off,
                                                att + i * HEADS * 32, bias + i * HID,
                                                xin, xo, xout,
                                                i > 0 ? 1 : 0, i < 3 ? 1 : 0, N);
    }

    k_reduce1<<<R1B, 256, 0, stream>>>(xout, N, psum, pmax);
    k_reduce2<<<1, 1024, 0, stream>>>(psum, pmax, R1B, out, 1.0f / N);
}

// Round 12
// 435.915 us; speedup vs baseline: 1.5239x; 1.1484x over previous
//
#include <hip/hip_runtime.h>
#include <math.h>

#define HID 128
#define HEADS 4
#define NEG_SLOPE 0.2f
#define R1B 1024   // reduce1 grid
#define BCAP 8192  // per-bucket arena capacity (mean 4096, +64 sigma)
#define PB 6144    // binB LDS staging ints
#define ACHUNK 4096

typedef float f32x4 __attribute__((ext_vector_type(4)));
typedef _Float16 f16x8 __attribute__((ext_vector_type(8)));
typedef _Float16 f16x4 __attribute__((ext_vector_type(4)));
typedef _Float16 f16x2 __attribute__((ext_vector_type(2)));

#if defined(__has_builtin)
#if __has_builtin(__builtin_amdgcn_fdot2)
#define HAVE_FDOT2 1
#endif
#endif

// ---------------- CSR build: two-phase binned counting sort ----------------
// Edges binned by dst>>8 into per-bucket arenas (dense appends), then each
// bucket block builds node-level rowptr + coalesced csr_off from LDS.
// Replaces hist (random atomics) + 3-kernel scan + scatter (51 MB of 4B
// random-write line amplification).

__global__ __launch_bounds__(256) void k_zero_int(int* p, int n) {
    int i = blockIdx.x * blockDim.x + threadIdx.x;
    if (i < n) p[i] = 0;
}

// Phase A: bin 4096 edges/block into bucket arenas. Record = (src<<8)|(dst&255).
__global__ __launch_bounds__(256) void k_binA(const int* __restrict__ src, const int* __restrict__ dst,
                                              int E, int* __restrict__ gcnt, int* __restrict__ arena) {
    __shared__ int lh[256];
    __shared__ int lbase[256];
    __shared__ unsigned short lrank[ACHUNK];
    const int tid = threadIdx.x;
    lh[tid] = 0;
    __syncthreads();
    const int e0 = blockIdx.x * ACHUNK;
    #pragma unroll
    for (int i = 0; i < ACHUNK / 256; i++) {
        int e = e0 + i * 256 + tid;
        if (e < E) {
            int b = dst[e] >> 8;
            lrank[i * 256 + tid] = (unsigned short)atomicAdd(&lh[b], 1);
        }
    }
    __syncthreads();
    if (lh[tid] > 0) lbase[tid] = atomicAdd(&gcnt[tid], lh[tid]);
    __syncthreads();
    #pragma unroll
    for (int i = 0; i < ACHUNK / 256; i++) {
        int e = e0 + i * 256 + tid;
        if (e < E) {
            int d = dst[e];
            int b = d >> 8;
            arena[b * BCAP + lbase[b] + lrank[i * 256 + tid]] = (src[e] << 8) | (d & 255);
        }
    }
}

// exclusive scan of bucket counts -> bucket segment starts; rowptr[N]=E
__global__ __launch_bounds__(256) void k_scan_bk(const int* __restrict__ gcnt, int nbk,
                                                 int* __restrict__ bstart, int* __restrict__ rowptr,
                                                 int N, int E) {
    __shared__ int buf[256];
    int tid = threadIdx.x;
    int v = (tid < nbk) ? gcnt[tid] : 0;
    buf[tid] = v;
    __syncthreads();
    for (int off = 1; off < 256; off <<= 1) {
        int t = (tid >= off) ? buf[tid - off] : 0;
        __syncthreads();
        buf[tid] += t;
        __syncthreads();
    }
    bstart[tid] = buf[tid] - v;
    if (tid == 0) rowptr[N] = E;
}

// Phase B: per bucket -- node counts + scan in LDS -> rowptr; staged,
// coalesced csr_off dump. csr_off value = src*256 = record & ~255.
__global__ __launch_bounds__(256) void k_binB(const int* __restrict__ arena, const int* __restrict__ gcnt,
                                              const int* __restrict__ bstart, int N,
                                              int* __restrict__ rowptr, int* __restrict__ csr_off) {
    __shared__ int ncnt[256];
    __shared__ int sbuf[256];
    __shared__ int nstart[256];
    __shared__ int stage[PB];
    __shared__ unsigned short rk[BCAP];
    const int b = blockIdx.x, tid = threadIdx.x;
    const int cnt = gcnt[b];
    const int seg = bstart[b];
    ncnt[tid] = 0;
    __syncthreads();
    for (int k = tid; k < cnt; k += 256) {
        int v = arena[b * BCAP + k];
        rk[k] = (unsigned short)atomicAdd(&ncnt[v & 255], 1);
    }
    __syncthreads();
    int c = ncnt[tid];
    sbuf[tid] = c;
    __syncthreads();
    for (int off = 1; off < 256; off <<= 1) {
        int t = (tid >= off) ? sbuf[tid - off] : 0;
        __syncthreads();
        sbuf[tid] += t;
        __syncthreads();
    }
    int myStart = sbuf[tid] - c;   // exclusive
    nstart[tid] = myStart;
    int n = b * 256 + tid;
    if (n < N) rowptr[n] = seg + myStart;
    __syncthreads();
    for (int k = tid; k < cnt; k += 256) {
        int v = arena[b * BCAP + k];
        int pos = nstart[v & 255] + rk[k];
        int val = v & 0xFFFFFF00;
        if (pos < PB) stage[pos] = val;
        else          csr_off[seg + pos] = val;   // statistical overflow guard
    }
    __syncthreads();
    int lim = min(cnt, PB);
    for (int k = tid; k < lim; k += 256) csr_off[seg + k] = stage[k];
}

// ---------------- helpers ----------------

__device__ inline f16x2 absh2(f16x2 v) {
    unsigned u = __builtin_bit_cast(unsigned, v) & 0x7FFF7FFFu;
    return __builtin_bit_cast(f16x2, u);
}

// fp32 -> fp16 convert for both W matrices in one launch (blockIdx.y selects)
__global__ __launch_bounds__(256) void k_tof16(const float* __restrict__ a, const float* __restrict__ b,
                                               _Float16* __restrict__ oa, _Float16* __restrict__ ob, int n) {
    const float* x = blockIdx.y ? b : a;
    _Float16*    o = blockIdx.y ? ob : oa;
    int base = (blockIdx.x * 256 + threadIdx.x) * 4;
    if (base >= n) return;
    float4 v = *(const float4*)(x + base);
    f16x4 h = {(_Float16)v.x, (_Float16)v.y, (_Float16)v.z, (_Float16)v.w};
    *(f16x4*)(o + base) = h;
}

// ---------------- MFMA linear, LDS-resident fp16 W ----------------
// fp16 inputs, fp32 MFMA accumulate (rel err ~5e-4, inside the 0.02 budget).
// blockIdx.y: 0 -> xlh = x@Wl.T+bl ; 1 -> xrh = x@Wr.T+br (both fp16).
// Block = 512 threads (8 waves) = 128 nodes; W (32 KB fp16) staged in LDS
// with XOR-chunk swizzle (2-way bank aliasing = free, m136).

__global__ __launch_bounds__(512) void k_linear_mfma(
        const _Float16* __restrict__ xh,
        const _Float16* __restrict__ WfL, const _Float16* __restrict__ WfR,
        const float* __restrict__ bl, const float* __restrict__ br,
        _Float16* __restrict__ xlh, _Float16* __restrict__ xrh, int N) {
    __shared__ _Float16 lds[16384];   // 32 KB: W fp16, swizzled
    const int t   = threadIdx.x;
    const int mat = blockIdx.y;
    const _Float16* W = mat ? WfR : WfL;

    for (int g = t; g < 2048; g += 512) {
        int r = g >> 4, cc = g & 15;
        int dsto = r * 128 + ((cc ^ (r & 7)) << 3);      // half units
        *(float4*)&lds[dsto] = *(const float4*)(W + g * 8);
    }
    __syncthreads();

    const int wave = t >> 6;
    const int lane = t & 63;
    const int l16  = lane & 15;
    const int quad = lane >> 4;
    const int n0   = blockIdx.x * 128 + wave * 16;

    int arow = n0 + l16;
    if (arow >= N) arow = N - 1;       // clamp loads; stores guarded below

    f32x4 acc[8];
    #pragma unroll
    for (int s = 0; s < 8; s++) acc[s] = (f32x4){0.f, 0.f, 0.f, 0.f};

    #pragma unroll
    for (int k0 = 0; k0 < HID; k0 += 32) {
        f16x8 a = *(const f16x8*)(xh + arow * HID + k0 + quad * 8);
        const int cc = (k0 >> 3) + quad;
        #pragma unroll
        for (int s = 0; s < 8; s++) {
            const int row = s * 16 + l16;
            const int off = row * 128 + ((cc ^ (l16 & 7)) << 3);
            f16x8 b = *(const f16x8*)&lds[off];
            acc[s] = __builtin_amdgcn_mfma_f32_16x16x32_f16(a, b, acc[s], 0, 0, 0);
        }
    }

    const float* bias = mat ? br : bl;
    _Float16* dst = mat ? xrh : xlh;
    #pragma unroll
    for (int s = 0; s < 8; s++) {
        int col = s * 16 + l16;
        float bv = bias[col];
        #pragma unroll
        for (int r = 0; r < 4; r++) {
            int node = n0 + quad * 4 + r;
            if (node < N) dst[(size_t)node * HID + col] = (_Float16)(acc[s][r] + bv);
        }
    }
}

// ---------------- Fused attention: wave per node, 4 edge streams ----------------

__global__ __launch_bounds__(256) void k_attn(const _Float16* __restrict__ xlh, const _Float16* __restrict__ xrh,
                                              const int* __restrict__ rowptr, const int* __restrict__ csr_off,
                                              const float* __restrict__ att, const float* __restrict__ bias,
                                              const _Float16* __restrict__ xres, _Float16* __restrict__ outx,
                                              float* __restrict__ out,
                                              int add_res, int want_half, int N) {
    const int wave = threadIdx.x >> 6;
    const int lane = threadIdx.x & 63;
    const int strm = lane >> 4;          // edge stream 0..3
    const int l16  = lane & 15;          // channels [8*l16, 8*l16+8); head = l16>>2
    const int n = blockIdx.x * 4 + wave;
    if (n >= N) return;

    const float4 aA = *(const float4*)(att + 8 * l16);
    const float4 aB = *(const float4*)(att + 8 * l16 + 4);
    const f16x2 a0 = (f16x2){(_Float16)aA.x, (_Float16)aA.y};
    const f16x2 a1 = (f16x2){(_Float16)aA.z, (_Float16)aA.w};
    const f16x2 a2 = (f16x2){(_Float16)aB.x, (_Float16)aB.y};
    const f16x2 a3 = (f16x2){(_Float16)aB.z, (_Float16)aB.w};
    const f16x8 xrv = *(const f16x8*)(xrh + (size_t)n * HID + 8 * l16);
    const f16x2 xr0 = __builtin_shufflevector(xrv, xrv, 0, 1);
    const f16x2 xr1 = __builtin_shufflevector(xrv, xrv, 2, 3);
    const f16x2 xr2 = __builtin_shufflevector(xrv, xrv, 4, 5);
    const f16x2 xr3 = __builtin_shufflevector(xrv, xrv, 6, 7);
    const f16x2 k06 = (f16x2){(_Float16)0.6f, (_Float16)0.6f};
    const f16x2 k04 = (f16x2){(_Float16)0.4f, (_Float16)0.4f};
    const int s0 = rowptr[n], s1 = rowptr[n + 1];

    float den = 0.f;
    float acc[8];
    #pragma unroll
    for (int q = 0; q < 8; q++) acc[q] = 0.f;

    const char* xlb = (const char*)xlh + l16 * 16;  // lane's 16B slice within a row

    int j = s0 + strm;
    if (j < s1) {
        const int last = s1 - 1;
        f16x8 p0 = *(const f16x8*)(xlb + csr_off[min(j,     last)]);
        f16x8 p1 = *(const f16x8*)(xlb + csr_off[min(j + 4, last)]);
        int   o2 = csr_off[min(j + 8, last)];
        while (j < s1) {
            f16x8 cur = p0;
            p0 = p1;
            p1 = *(const f16x8*)(xlb + o2);
            o2 = csr_off[min(j + 12, last)];

            f16x2 c0 = __builtin_shufflevector(cur, cur, 0, 1);
            f16x2 c1 = __builtin_shufflevector(cur, cur, 2, 3);
            f16x2 c2 = __builtin_shufflevector(cur, cur, 4, 5);
            f16x2 c3 = __builtin_shufflevector(cur, cur, 6, 7);
            f16x2 u0 = c0 + xr0, u1 = c1 + xr1, u2 = c2 + xr2, u3 = c3 + xr3;
            f16x2 l0 = u0 * k06 + absh2(u0) * k04;   // leaky_relu, packed
            f16x2 l1 = u1 * k06 + absh2(u1) * k04;
            f16x2 l2 = u2 * k06 + absh2(u2) * k04;
            f16x2 l3 = u3 * k06 + absh2(u3) * k04;
#ifdef HAVE_FDOT2
            float p = __builtin_amdgcn_fdot2(l0, a0, 0.f, false);
            p = __builtin_amdgcn_fdot2(l1, a1, p, false);
            p = __builtin_amdgcn_fdot2(l2, a2, p, false);
            p = __builtin_amdgcn_fdot2(l3, a3, p, false);
#else
            float p = (float)l0[0] * (float)a0[0] + (float)l0[1] * (float)a0[1]
                    + (float)l1[0] * (float)a1[0] + (float)l1[1] * (float)a1[1]
                    + (float)l2[0] * (float)a2[0] + (float)l2[1] * (float)a2[1]
                    + (float)l3[0] * (float)a3[0] + (float)l3[1] * (float)a3[1];
#endif
            p += __shfl_xor(p, 1);           // reduce 4-lane head group
            p += __shfl_xor(p, 2);
            float w = __expf(p);
            den += w;
            #pragma unroll
            for (int q = 0; q < 8; q++) acc[q] += w * (float)cur[q];
            j += 4;
        }
    }

    // merge the four streams (lane stride 16/32)
    den += __shfl_xor(den, 16);
    den += __shfl_xor(den, 32);
    #pragma unroll
    for (int q = 0; q < 8; q++) {
        acc[q] += __shfl_xor(acc[q], 16);
        acc[q] += __shfl_xor(acc[q], 32);
    }

    if (strm == 0) {
        float4 bA = *(const float4*)(bias + 8 * l16);
        float4 bB = *(const float4*)(bias + 8 * l16 + 4);
        float b[8] = {bA.x, bA.y, bA.z, bA.w, bB.x, bB.y, bB.z, bB.w};
        float inv = (den > 0.f) ? 1.f / den : 0.f;
        float v[8];
        #pragma unroll
        for (int q = 0; q < 8; q++) v[q] = fmaxf(acc[q] * inv + b[q], 0.f);
        if (add_res) {
            f16x8 r = *(const f16x8*)(xres + (size_t)n * HID + 8 * l16);
            #pragma unroll
            for (int q = 0; q < 8; q++) v[q] += (float)r[q];
        }
        if (want_half) {
            f16x8 h;
            #pragma unroll
            for (int q = 0; q < 8; q++) h[q] = (_Float16)v[q];
            *(f16x8*)(outx + (size_t)n * HID + 8 * l16) = h;
        } else {
            *(float4*)(out + (size_t)n * HID + 8 * l16)     = make_float4(v[0], v[1], v[2], v[3]);
            *(float4*)(out + (size_t)n * HID + 8 * l16 + 4) = make_float4(v[4], v[5], v[6], v[7]);
        }
    }
}

// ---------------- Embedding: x = relu(nf @ W_emb.T + b_emb) -> fp16 ----------------

__global__ __launch_bounds__(128) void k_embed(const float* __restrict__ nf, const float* __restrict__ W,
                                               const float* __restrict__ b,
                                               _Float16* __restrict__ xh, int N) {
    __shared__ float f[11];
    int n = blockIdx.x;
    int h = threadIdx.x;
    if (h < 11) f[h] = nf[(size_t)n * 11 + h];
    __syncthreads();
    float acc = b[h];
    #pragma unroll
    for (int k = 0; k < 11; k++) acc += f[k] * W[h * 11 + k];
    xh[(size_t)n * HID + h] = (_Float16)fmaxf(acc, 0.f);
}

// ---------------- Graph readout: mean + max over nodes ----------------

__global__ __launch_bounds__(256) void k_reduce1(const float* __restrict__ x, int N,
                                                 float* __restrict__ psum, float* __restrict__ pmax) {
    __shared__ float ls[8][HID];
    __shared__ float lm[8][HID];
    const int c4 = (threadIdx.x & 31) << 2;   // channel base
    const int rl = threadIdx.x >> 5;          // row lane 0..7
    const int per = (N + gridDim.x - 1) / gridDim.x;
    const int n0 = blockIdx.x * per, n1 = min(N, n0 + per);
    float4 s = make_float4(0.f, 0.f, 0.f, 0.f);
    float4 m = make_float4(-INFINITY, -INFINITY, -INFINITY, -INFINITY);
    for (int n = n0 + rl; n < n1; n += 8) {
        float4 v = *(const float4*)(x + (size_t)n * HID + c4);
        s.x += v.x; s.y += v.y; s.z += v.z; s.w += v.w;
        m.x = fmaxf(m.x, v.x); m.y = fmaxf(m.y, v.y);
        m.z = fmaxf(m.z, v.z); m.w = fmaxf(m.w, v.w);
    }
    *(float4*)&ls[rl][c4] = s;
    *(float4*)&lm[rl][c4] = m;
    __syncthreads();
    if (rl < 4) {
        float4 a = *(float4*)&ls[rl][c4], bq = *(float4*)&ls[rl + 4][c4];
        a.x += bq.x; a.y += bq.y; a.z += bq.z; a.w += bq.w;
        *(float4*)&ls[rl][c4] = a;
        float4 am = *(float4*)&lm[rl][c4], bm = *(float4*)&lm[rl + 4][c4];
        am.x = fmaxf(am.x, bm.x); am.y = fmaxf(am.y, bm.y);
        am.z = fmaxf(am.z, bm.z); am.w = fmaxf(am.w, bm.w);
        *(float4*)&lm[rl][c4] = am;
    }
    __syncthreads();
    if (rl < 2) {
        float4 a = *(float4*)&ls[rl][c4], bq = *(float4*)&ls[rl + 2][c4];
        a.x += bq.x; a.y += bq.y; a.z += bq.z; a.w += bq.w;
        *(float4*)&ls[rl][c4] = a;
        float4 am = *(float4*)&lm[rl][c4], bm = *(float4*)&lm[rl + 2][c4];
        am.x = fmaxf(am.x, bm.x); am.y = fmaxf(am.y, bm.y);
        am.z = fmaxf(am.z, bm.z); am.w = fmaxf(am.w, bm.w);
        *(float4*)&lm[rl][c4] = am;
    }
    __syncthreads();
    if (rl == 0) {
        float4 a = *(float4*)&ls[0][c4], bq = *(float4*)&ls[1][c4];
        a.x += bq.x; a.y += bq.y; a.z += bq.z; a.w += bq.w;
        *(float4*)(psum + (size_t)blockIdx.x * HID + c4) = a;
        float4 am = *(float4*)&lm[0][c4], bm = *(float4*)&lm[1][c4];
        am.x = fmaxf(am.x, bm.x); am.y = fmaxf(am.y, bm.y);
        am.z = fmaxf(am.z, bm.z); am.w = fmaxf(am.w, bm.w);
        *(float4*)(pmax + (size_t)blockIdx.x * HID + c4) = am;
    }
}

__global__ __launch_bounds__(1024) void k_reduce2(const float* __restrict__ psum, const float* __restrict__ pmax,
                                                  int nb, float* __restrict__ out, float invN) {
    __shared__ float ss[8][HID];
    __shared__ float sm[8][HID];
    int h = threadIdx.x & 127;
    int c = threadIdx.x >> 7;          // chunk 0..7
    int per = nb >> 3;
    float s = 0.f, m = -INFINITY;
    for (int b = c * per; b < (c + 1) * per; b++) {
        s += psum[b * HID + h];
        m = fmaxf(m, pmax[b * HID + h]);
    }
    ss[c][h] = s; sm[c][h] = m;
    __syncthreads();
    if (c < 4) { ss[c][h] += ss[c + 4][h]; sm[c][h] = fmaxf(sm[c][h], sm[c + 4][h]); }
    __syncthreads();
    if (c < 2) { ss[c][h] += ss[c + 2][h]; sm[c][h] = fmaxf(sm[c][h], sm[c + 2][h]); }
    __syncthreads();
    if (c == 0) {
        out[h] = (ss[0][h] + ss[1][h]) * invN;
        out[HID + h] = fmaxf(sm[0][h], sm[1][h]);
    }
}

// ---------------- Launch ----------------

extern "C" void kernel_launch(void* const* d_in, const int* in_sizes, int n_in,
                              void* d_out, int out_size, void* d_ws, size_t ws_size,
                              hipStream_t stream) {
    const float* nf    = (const float*)d_in[0];
    const int*   ei    = (const int*)d_in[1];
    const float* W_emb = (const float*)d_in[3];
    const float* b_emb = (const float*)d_in[4];
    const float* Wl    = (const float*)d_in[5];
    const float* bl    = (const float*)d_in[6];
    const float* Wr    = (const float*)d_in[7];
    const float* br    = (const float*)d_in[8];
    const float* att   = (const float*)d_in[9];
    const float* bias  = (const float*)d_in[10];

    const int N = in_sizes[0] / 11;
    const int E = in_sizes[1] / 2;
    const int* src = ei;
    const int* dst = ei + E;

    float* out  = (float*)d_out;
    float* xout = out + 2 * HID;

    // workspace carve-up
    char* w = (char*)d_ws;
    _Float16* xlh  = (_Float16*)w; w += (size_t)N * HID * 2;
    _Float16* xrh  = (_Float16*)w; w += (size_t)N * HID * 2;
    _Float16* xA   = (_Float16*)w; w += (size_t)N * HID * 2;
    _Float16* xB   = (_Float16*)w; w += (size_t)N * HID * 2;
    _Float16* WfL  = (_Float16*)w; w += (size_t)4 * HID * HID * 2;
    _Float16* WfR  = (_Float16*)w; w += (size_t)4 * HID * HID * 2;
    int*   gcnt    = (int*)w;   w += (size_t)256 * 4;
    int*   bstart  = (int*)w;   w += (size_t)256 * 4;
    int*   rowptr  = (int*)w;   w += (size_t)(N + 1) * 4;
    int*   arena   = (int*)w;   w += (size_t)256 * BCAP * 4;
    int*   csr_off = (int*)w;   w += (size_t)E * 4;
    float* psum    = (float*)w; w += (size_t)R1B * HID * 4;
    float* pmax    = (float*)w; w += (size_t)R1B * HID * 4;

    const int nbk = (N + 255) >> 8;       // 196 buckets
    const int nW = 4 * HID * HID;

    // weight fp16 conversion (both matrices, one launch)
    dim3 tg((nW / 4 + 255) / 256, 2);
    k_tof16<<<tg, 256, 0, stream>>>(Wl, Wr, WfL, WfR, nW);

    // CSR build (binned two-phase)
    k_zero_int<<<1, 256, 0, stream>>>(gcnt, 256);
    k_binA<<<(E + ACHUNK - 1) / ACHUNK, 256, 0, stream>>>(src, dst, E, gcnt, arena);
    k_scan_bk<<<1, 256, 0, stream>>>(gcnt, nbk, bstart, rowptr, N, E);
    k_binB<<<nbk, 256, 0, stream>>>(arena, gcnt, bstart, N, rowptr, csr_off);

    // embedding -> fp16 x (buffer A)
    k_embed<<<N, 128, 0, stream>>>(nf, W_emb, b_emb, xA, N);

    dim3 lgrid((N + 127) / 128, 2);
    for (int i = 0; i < 4; i++) {
        // ping-pong: even layers read A write B, odd layers read B write A
        const _Float16* xin = (i & 1) ? xB : xA;
        _Float16* xo        = (i & 1) ? xA : xB;
        k_linear_mfma<<<lgrid, 512, 0, stream>>>(xin,
                                                 WfL + (size_t)i * HID * HID, WfR + (size_t)i * HID * HID,
                                                 bl + i * HID, br + i * HID, xlh, xrh, N);
        k_attn<<<(N + 3) / 4, 256, 0, stream>>>(xlh, xrh, rowptr, csr_off,
                                                att + i * HEADS * 32, bias + i * HID,
                                                xin, xo, xout,
                                                i > 0 ? 1 : 0, i < 3 ? 1 : 0, N);
    }

    k_reduce1<<<R1B, 256, 0, stream>>>(xout, N, psum, pmax);
    k_reduce2<<<1, 1024, 0, stream>>>(psum, pmax, R1B, out, 1.0f / N);
}

// Round 13
// 426.058 us; speedup vs baseline: 1.5591x; 1.0231x over previous
//
#include <hip/hip_runtime.h>
#include <math.h>

#define HID 128
#define HEADS 4
#define NEG_SLOPE 0.2f
#define R1B 1024   // reduce1 grid
#define BCAP 8192  // per-bucket arena capacity (mean 4096, +64 sigma)
#define PB 6144    // binB LDS staging ints
#define ACHUNK 4096

typedef float f32x4 __attribute__((ext_vector_type(4)));
typedef _Float16 f16x8 __attribute__((ext_vector_type(8)));
typedef _Float16 f16x4 __attribute__((ext_vector_type(4)));
typedef _Float16 f16x2 __attribute__((ext_vector_type(2)));

#if defined(__has_builtin)
#if __has_builtin(__builtin_amdgcn_fdot2)
#define HAVE_FDOT2 1
#endif
#endif

// ---------------- CSR build: two-phase binned counting sort ----------------

__global__ __launch_bounds__(256) void k_zero_int(int* p, int n) {
    int i = blockIdx.x * blockDim.x + threadIdx.x;
    if (i < n) p[i] = 0;
}

// Phase A: bin 4096 edges/block into bucket arenas. Record = (src<<8)|(dst&255).
__global__ __launch_bounds__(256) void k_binA(const int* __restrict__ src, const int* __restrict__ dst,
                                              int E, int* __restrict__ gcnt, int* __restrict__ arena) {
    __shared__ int lh[256];
    __shared__ int lbase[256];
    __shared__ unsigned short lrank[ACHUNK];
    const int tid = threadIdx.x;
    lh[tid] = 0;
    __syncthreads();
    const int e0 = blockIdx.x * ACHUNK;
    #pragma unroll
    for (int i = 0; i < ACHUNK / 256; i++) {
        int e = e0 + i * 256 + tid;
        if (e < E) {
            int b = dst[e] >> 8;
            lrank[i * 256 + tid] = (unsigned short)atomicAdd(&lh[b], 1);
        }
    }
    __syncthreads();
    if (lh[tid] > 0) lbase[tid] = atomicAdd(&gcnt[tid], lh[tid]);
    __syncthreads();
    #pragma unroll
    for (int i = 0; i < ACHUNK / 256; i++) {
        int e = e0 + i * 256 + tid;
        if (e < E) {
            int d = dst[e];
            int b = d >> 8;
            arena[b * BCAP + lbase[b] + lrank[i * 256 + tid]] = (src[e] << 8) | (d & 255);
        }
    }
}

// exclusive scan of bucket counts -> bucket segment starts; rowptr[N]=E
__global__ __launch_bounds__(256) void k_scan_bk(const int* __restrict__ gcnt, int nbk,
                                                 int* __restrict__ bstart, int* __restrict__ rowptr,
                                                 int N, int E) {
    __shared__ int buf[256];
    int tid = threadIdx.x;
    int v = (tid < nbk) ? gcnt[tid] : 0;
    buf[tid] = v;
    __syncthreads();
    for (int off = 1; off < 256; off <<= 1) {
        int t = (tid >= off) ? buf[tid - off] : 0;
        __syncthreads();
        buf[tid] += t;
        __syncthreads();
    }
    bstart[tid] = buf[tid] - v;
    if (tid == 0) rowptr[N] = E;
}

// Phase B: per bucket -- node counts + scan in LDS -> rowptr; staged,
// coalesced csr_off dump. csr_off value = src*256 = record & ~255.
__global__ __launch_bounds__(256) void k_binB(const int* __restrict__ arena, const int* __restrict__ gcnt,
                                              const int* __restrict__ bstart, int N,
                                              int* __restrict__ rowptr, int* __restrict__ csr_off) {
    __shared__ int ncnt[256];
    __shared__ int sbuf[256];
    __shared__ int nstart[256];
    __shared__ int stage[PB];
    __shared__ unsigned short rk[BCAP];
    const int b = blockIdx.x, tid = threadIdx.x;
    const int cnt = gcnt[b];
    const int seg = bstart[b];
    ncnt[tid] = 0;
    __syncthreads();
    for (int k = tid; k < cnt; k += 256) {
        int v = arena[b * BCAP + k];
        rk[k] = (unsigned short)atomicAdd(&ncnt[v & 255], 1);
    }
    __syncthreads();
    int c = ncnt[tid];
    sbuf[tid] = c;
    __syncthreads();
    for (int off = 1; off < 256; off <<= 1) {
        int t = (tid >= off) ? sbuf[tid - off] : 0;
        __syncthreads();
        sbuf[tid] += t;
        __syncthreads();
    }
    int myStart = sbuf[tid] - c;   // exclusive
    nstart[tid] = myStart;
    int n = b * 256 + tid;
    if (n < N) rowptr[n] = seg + myStart;
    __syncthreads();
    for (int k = tid; k < cnt; k += 256) {
        int v = arena[b * BCAP + k];
        int pos = nstart[v & 255] + rk[k];
        int val = v & 0xFFFFFF00;
        if (pos < PB) stage[pos] = val;
        else          csr_off[seg + pos] = val;   // statistical overflow guard
    }
    __syncthreads();
    int lim = min(cnt, PB);
    for (int k = tid; k < lim; k += 256) csr_off[seg + k] = stage[k];
}

// ---------------- helpers ----------------

__device__ inline f16x2 absh2(f16x2 v) {
    unsigned u = __builtin_bit_cast(unsigned, v) & 0x7FFF7FFFu;
    return __builtin_bit_cast(f16x2, u);
}

// fp32 -> fp16 convert for both W matrices in one launch (blockIdx.y selects)
__global__ __launch_bounds__(256) void k_tof16(const float* __restrict__ a, const float* __restrict__ b,
                                               _Float16* __restrict__ oa, _Float16* __restrict__ ob, int n) {
    const float* x = blockIdx.y ? b : a;
    _Float16*    o = blockIdx.y ? ob : oa;
    int base = (blockIdx.x * 256 + threadIdx.x) * 4;
    if (base >= n) return;
    float4 v = *(const float4*)(x + base);
    f16x4 h = {(_Float16)v.x, (_Float16)v.y, (_Float16)v.z, (_Float16)v.w};
    *(f16x4*)(o + base) = h;
}

// ---------------- MFMA linear, LDS-resident fp16 W, 2 A-tiles/wave ----------------
// fp16 inputs, fp32 MFMA accumulate. blockIdx.y: 0 -> xlh ; 1 -> xrh.
// Wave covers 32 nodes x 128 outputs: each ds_read_b128 B-fragment feeds
// TWO MFMAs (ds throughput was the k-loop bottleneck: 8x12cyc ds vs 8x4.85cyc
// MFMA; now 96 ds vs 78 MFMA per k0 - balanced). Block = 512 thr = 256 nodes.

__global__ __launch_bounds__(512) void k_linear_mfma(
        const _Float16* __restrict__ xh,
        const _Float16* __restrict__ WfL, const _Float16* __restrict__ WfR,
        const float* __restrict__ bl, const float* __restrict__ br,
        _Float16* __restrict__ xlh, _Float16* __restrict__ xrh, int N) {
    __shared__ _Float16 lds[16384];   // 32 KB: W fp16, swizzled
    const int t   = threadIdx.x;
    const int mat = blockIdx.y;
    const _Float16* W = mat ? WfR : WfL;

    for (int g = t; g < 2048; g += 512) {
        int r = g >> 4, cc = g & 15;
        int dsto = r * 128 + ((cc ^ (r & 7)) << 3);      // half units
        *(float4*)&lds[dsto] = *(const float4*)(W + g * 8);
    }
    __syncthreads();

    const int wave = t >> 6;
    const int lane = t & 63;
    const int l16  = lane & 15;
    const int quad = lane >> 4;
    const int n0   = blockIdx.x * 256 + wave * 32;

    int arow0 = n0 + l16;
    int arow1 = n0 + 16 + l16;
    if (arow0 >= N) arow0 = N - 1;     // clamp loads; stores guarded below
    if (arow1 >= N) arow1 = N - 1;

    f32x4 acc[2][8];
    #pragma unroll
    for (int u = 0; u < 2; u++)
        #pragma unroll
        for (int s = 0; s < 8; s++) acc[u][s] = (f32x4){0.f, 0.f, 0.f, 0.f};

    #pragma unroll
    for (int k0 = 0; k0 < HID; k0 += 32) {
        f16x8 a0 = *(const f16x8*)(xh + arow0 * HID + k0 + quad * 8);
        f16x8 a1 = *(const f16x8*)(xh + arow1 * HID + k0 + quad * 8);
        const int cc = (k0 >> 3) + quad;
        #pragma unroll
        for (int s = 0; s < 8; s++) {
            const int row = s * 16 + l16;
            const int off = row * 128 + ((cc ^ (l16 & 7)) << 3);
            f16x8 b = *(const f16x8*)&lds[off];
            acc[0][s] = __builtin_amdgcn_mfma_f32_16x16x32_f16(a0, b, acc[0][s], 0, 0, 0);
            acc[1][s] = __builtin_amdgcn_mfma_f32_16x16x32_f16(a1, b, acc[1][s], 0, 0, 0);
        }
    }

    const float* bias = mat ? br : bl;
    _Float16* dst = mat ? xrh : xlh;
    #pragma unroll
    for (int s = 0; s < 8; s++) {
        int col = s * 16 + l16;
        float bv = bias[col];
        #pragma unroll
        for (int u = 0; u < 2; u++) {
            #pragma unroll
            for (int r = 0; r < 4; r++) {
                int node = n0 + u * 16 + quad * 4 + r;
                if (node < N) dst[(size_t)node * HID + col] = (_Float16)(acc[u][s][r] + bv);
            }
        }
    }
}

// ---------------- Fused attention: wave per node, 4 edge streams ----------------
// fp16 packed accumulate (4 v_pk_fma vs 8 cvt + 8 fma fp32): ~25% fewer
// per-edge VALU ops; error ~1e-3 abs, inside the 0.02 budget.

__global__ __launch_bounds__(256) void k_attn(const _Float16* __restrict__ xlh, const _Float16* __restrict__ xrh,
                                              const int* __restrict__ rowptr, const int* __restrict__ csr_off,
                                              const float* __restrict__ att, const float* __restrict__ bias,
                                              const _Float16* __restrict__ xres, _Float16* __restrict__ outx,
                                              float* __restrict__ out,
                                              int add_res, int want_half, int N) {
    const int wave = threadIdx.x >> 6;
    const int lane = threadIdx.x & 63;
    const int strm = lane >> 4;          // edge stream 0..3
    const int l16  = lane & 15;          // channels [8*l16, 8*l16+8); head = l16>>2
    const int n = blockIdx.x * 4 + wave;
    if (n >= N) return;

    const float4 aA = *(const float4*)(att + 8 * l16);
    const float4 aB = *(const float4*)(att + 8 * l16 + 4);
    const f16x2 a0 = (f16x2){(_Float16)aA.x, (_Float16)aA.y};
    const f16x2 a1 = (f16x2){(_Float16)aA.z, (_Float16)aA.w};
    const f16x2 a2 = (f16x2){(_Float16)aB.x, (_Float16)aB.y};
    const f16x2 a3 = (f16x2){(_Float16)aB.z, (_Float16)aB.w};
    const f16x8 xrv = *(const f16x8*)(xrh + (size_t)n * HID + 8 * l16);
    const f16x2 xr0 = __builtin_shufflevector(xrv, xrv, 0, 1);
    const f16x2 xr1 = __builtin_shufflevector(xrv, xrv, 2, 3);
    const f16x2 xr2 = __builtin_shufflevector(xrv, xrv, 4, 5);
    const f16x2 xr3 = __builtin_shufflevector(xrv, xrv, 6, 7);
    const f16x2 k06 = (f16x2){(_Float16)0.6f, (_Float16)0.6f};
    const f16x2 k04 = (f16x2){(_Float16)0.4f, (_Float16)0.4f};
    const int s0 = rowptr[n], s1 = rowptr[n + 1];

    float den = 0.f;
    f16x2 acc16[4];
    #pragma unroll
    for (int q = 0; q < 4; q++) acc16[q] = (f16x2){(_Float16)0.f, (_Float16)0.f};

    const char* xlb = (const char*)xlh + l16 * 16;  // lane's 16B slice within a row

    int j = s0 + strm;
    if (j < s1) {
        const int last = s1 - 1;
        f16x8 p0 = *(const f16x8*)(xlb + csr_off[min(j,     last)]);
        f16x8 p1 = *(const f16x8*)(xlb + csr_off[min(j + 4, last)]);
        int   o2 = csr_off[min(j + 8, last)];
        while (j < s1) {
            f16x8 cur = p0;
            p0 = p1;
            p1 = *(const f16x8*)(xlb + o2);
            o2 = csr_off[min(j + 12, last)];

            f16x2 c0 = __builtin_shufflevector(cur, cur, 0, 1);
            f16x2 c1 = __builtin_shufflevector(cur, cur, 2, 3);
            f16x2 c2 = __builtin_shufflevector(cur, cur, 4, 5);
            f16x2 c3 = __builtin_shufflevector(cur, cur, 6, 7);
            f16x2 u0 = c0 + xr0, u1 = c1 + xr1, u2 = c2 + xr2, u3 = c3 + xr3;
            f16x2 l0 = u0 * k06 + absh2(u0) * k04;   // leaky_relu, packed
            f16x2 l1 = u1 * k06 + absh2(u1) * k04;
            f16x2 l2 = u2 * k06 + absh2(u2) * k04;
            f16x2 l3 = u3 * k06 + absh2(u3) * k04;
#ifdef HAVE_FDOT2
            float p = __builtin_amdgcn_fdot2(l0, a0, 0.f, false);
            p = __builtin_amdgcn_fdot2(l1, a1, p, false);
            p = __builtin_amdgcn_fdot2(l2, a2, p, false);
            p = __builtin_amdgcn_fdot2(l3, a3, p, false);
#else
            float p = (float)l0[0] * (float)a0[0] + (float)l0[1] * (float)a0[1]
                    + (float)l1[0] * (float)a1[0] + (float)l1[1] * (float)a1[1]
                    + (float)l2[0] * (float)a2[0] + (float)l2[1] * (float)a2[1]
                    + (float)l3[0] * (float)a3[0] + (float)l3[1] * (float)a3[1];
#endif
            p += __shfl_xor(p, 1);           // reduce 4-lane head group
            p += __shfl_xor(p, 2);
            float w = __expf(p);
            den += w;
            _Float16 wh = (_Float16)w;
            f16x2 wp = (f16x2){wh, wh};
            acc16[0] += wp * c0;             // v_pk_fma_f16
            acc16[1] += wp * c1;
            acc16[2] += wp * c2;
            acc16[3] += wp * c3;
            j += 4;
        }
    }

    float acc[8];
    #pragma unroll
    for (int q = 0; q < 4; q++) {
        acc[2 * q]     = (float)acc16[q][0];
        acc[2 * q + 1] = (float)acc16[q][1];
    }

    // merge the four streams (lane stride 16/32)
    den += __shfl_xor(den, 16);
    den += __shfl_xor(den, 32);
    #pragma unroll
    for (int q = 0; q < 8; q++) {
        acc[q] += __shfl_xor(acc[q], 16);
        acc[q] += __shfl_xor(acc[q], 32);
    }

    if (strm == 0) {
        float4 bA = *(const float4*)(bias + 8 * l16);
        float4 bB = *(const float4*)(bias + 8 * l16 + 4);
        float b[8] = {bA.x, bA.y, bA.z, bA.w, bB.x, bB.y, bB.z, bB.w};
        float inv = (den > 0.f) ? 1.f / den : 0.f;
        float v[8];
        #pragma unroll
        for (int q = 0; q < 8; q++) v[q] = fmaxf(acc[q] * inv + b[q], 0.f);
        if (add_res) {
            f16x8 r = *(const f16x8*)(xres + (size_t)n * HID + 8 * l16);
            #pragma unroll
            for (int q = 0; q < 8; q++) v[q] += (float)r[q];
        }
        if (want_half) {
            f16x8 h;
            #pragma unroll
            for (int q = 0; q < 8; q++) h[q] = (_Float16)v[q];
            *(f16x8*)(outx + (size_t)n * HID + 8 * l16) = h;
        } else {
            *(float4*)(out + (size_t)n * HID + 8 * l16)     = make_float4(v[0], v[1], v[2], v[3]);
            *(float4*)(out + (size_t)n * HID + 8 * l16 + 4) = make_float4(v[4], v[5], v[6], v[7]);
        }
    }
}

// ---------------- Embedding: x = relu(nf @ W_emb.T + b_emb) -> fp16 ----------------

__global__ __launch_bounds__(128) void k_embed(const float* __restrict__ nf, const float* __restrict__ W,
                                               const float* __restrict__ b,
                                               _Float16* __restrict__ xh, int N) {
    __shared__ float f[11];
    int n = blockIdx.x;
    int h = threadIdx.x;
    if (h < 11) f[h] = nf[(size_t)n * 11 + h];
    __syncthreads();
    float acc = b[h];
    #pragma unroll
    for (int k = 0; k < 11; k++) acc += f[k] * W[h * 11 + k];
    xh[(size_t)n * HID + h] = (_Float16)fmaxf(acc, 0.f);
}

// ---------------- Graph readout: mean + max over nodes ----------------

__global__ __launch_bounds__(256) void k_reduce1(const float* __restrict__ x, int N,
                                                 float* __restrict__ psum, float* __restrict__ pmax) {
    __shared__ float ls[8][HID];
    __shared__ float lm[8][HID];
    const int c4 = (threadIdx.x & 31) << 2;   // channel base
    const int rl = threadIdx.x >> 5;          // row lane 0..7
    const int per = (N + gridDim.x - 1) / gridDim.x;
    const int n0 = blockIdx.x * per, n1 = min(N, n0 + per);
    float4 s = make_float4(0.f, 0.f, 0.f, 0.f);
    float4 m = make_float4(-INFINITY, -INFINITY, -INFINITY, -INFINITY);
    for (int n = n0 + rl; n < n1; n += 8) {
        float4 v = *(const float4*)(x + (size_t)n * HID + c4);
        s.x += v.x; s.y += v.y; s.z += v.z; s.w += v.w;
        m.x = fmaxf(m.x, v.x); m.y = fmaxf(m.y, v.y);
        m.z = fmaxf(m.z, v.z); m.w = fmaxf(m.w, v.w);
    }
    *(float4*)&ls[rl][c4] = s;
    *(float4*)&lm[rl][c4] = m;
    __syncthreads();
    if (rl < 4) {
        float4 a = *(float4*)&ls[rl][c4], bq = *(float4*)&ls[rl + 4][c4];
        a.x += bq.x; a.y += bq.y; a.z += bq.z; a.w += bq.w;
        *(float4*)&ls[rl][c4] = a;
        float4 am = *(float4*)&lm[rl][c4], bm = *(float4*)&lm[rl + 4][c4];
        am.x = fmaxf(am.x, bm.x); am.y = fmaxf(am.y, bm.y);
        am.z = fmaxf(am.z, bm.z); am.w = fmaxf(am.w, bm.w);
        *(float4*)&lm[rl][c4] = am;
    }
    __syncthreads();
    if (rl < 2) {
        float4 a = *(float4*)&ls[rl][c4], bq = *(float4*)&ls[rl + 2][c4];
        a.x += bq.x; a.y += bq.y; a.z += bq.z; a.w += bq.w;
        *(float4*)&ls[rl][c4] = a;
        float4 am = *(float4*)&lm[rl][c4], bm = *(float4*)&lm[rl + 2][c4];
        am.x = fmaxf(am.x, bm.x); am.y = fmaxf(am.y, bm.y);
        am.z = fmaxf(am.z, bm.z); am.w = fmaxf(am.w, bm.w);
        *(float4*)&lm[rl][c4] = am;
    }
    __syncthreads();
    if (rl == 0) {
        float4 a = *(float4*)&ls[0][c4], bq = *(float4*)&ls[1][c4];
        a.x += bq.x; a.y += bq.y; a.z += bq.z; a.w += bq.w;
        *(float4*)(psum + (size_t)blockIdx.x * HID + c4) = a;
        float4 am = *(float4*)&lm[0][c4], bm = *(float4*)&lm[1][c4];
        am.x = fmaxf(am.x, bm.x); am.y = fmaxf(am.y, bm.y);
        am.z = fmaxf(am.z, bm.z); am.w = fmaxf(am.w, bm.w);
        *(float4*)(pmax + (size_t)blockIdx.x * HID + c4) = am;
    }
}

__global__ __launch_bounds__(1024) void k_reduce2(const float* __restrict__ psum, const float* __restrict__ pmax,
                                                  int nb, float* __restrict__ out, float invN) {
    __shared__ float ss[8][HID];
    __shared__ float sm[8][HID];
    int h = threadIdx.x & 127;
    int c = threadIdx.x >> 7;          // chunk 0..7
    int per = nb >> 3;
    float s = 0.f, m = -INFINITY;
    for (int b = c * per; b < (c + 1) * per; b++) {
        s += psum[b * HID + h];
        m = fmaxf(m, pmax[b * HID + h]);
    }
    ss[c][h] = s; sm[c][h] = m;
    __syncthreads();
    if (c < 4) { ss[c][h] += ss[c + 4][h]; sm[c][h] = fmaxf(sm[c][h], sm[c + 4][h]); }
    __syncthreads();
    if (c < 2) { ss[c][h] += ss[c + 2][h]; sm[c][h] = fmaxf(sm[c][h], sm[c + 2][h]); }
    __syncthreads();
    if (c == 0) {
        out[h] = (ss[0][h] + ss[1][h]) * invN;
        out[HID + h] = fmaxf(sm[0][h], sm[1][h]);
    }
}

// ---------------- Launch ----------------

extern "C" void kernel_launch(void* const* d_in, const int* in_sizes, int n_in,
                              void* d_out, int out_size, void* d_ws, size_t ws_size,
                              hipStream_t stream) {
    const float* nf    = (const float*)d_in[0];
    const int*   ei    = (const int*)d_in[1];
    const float* W_emb = (const float*)d_in[3];
    const float* b_emb = (const float*)d_in[4];
    const float* Wl    = (const float*)d_in[5];
    const float* bl    = (const float*)d_in[6];
    const float* Wr    = (const float*)d_in[7];
    const float* br    = (const float*)d_in[8];
    const float* att   = (const float*)d_in[9];
    const float* bias  = (const float*)d_in[10];

    const int N = in_sizes[0] / 11;
    const int E = in_sizes[1] / 2;
    const int* src = ei;
    const int* dst = ei + E;

    float* out  = (float*)d_out;
    float* xout = out + 2 * HID;

    // workspace carve-up
    char* w = (char*)d_ws;
    _Float16* xlh  = (_Float16*)w; w += (size_t)N * HID * 2;
    _Float16* xrh  = (_Float16*)w; w += (size_t)N * HID * 2;
    _Float16* xA   = (_Float16*)w; w += (size_t)N * HID * 2;
    _Float16* xB   = (_Float16*)w; w += (size_t)N * HID * 2;
    _Float16* WfL  = (_Float16*)w; w += (size_t)4 * HID * HID * 2;
    _Float16* WfR  = (_Float16*)w; w += (size_t)4 * HID * HID * 2;
    int*   gcnt    = (int*)w;   w += (size_t)256 * 4;
    int*   bstart  = (int*)w;   w += (size_t)256 * 4;
    int*   rowptr  = (int*)w;   w += (size_t)(N + 1) * 4;
    int*   arena   = (int*)w;   w += (size_t)256 * BCAP * 4;
    int*   csr_off = (int*)w;   w += (size_t)E * 4;
    float* psum    = (float*)w; w += (size_t)R1B * HID * 4;
    float* pmax    = (float*)w; w += (size_t)R1B * HID * 4;

    const int nbk = (N + 255) >> 8;       // 196 buckets
    const int nW = 4 * HID * HID;

    // weight fp16 conversion (both matrices, one launch)
    dim3 tg((nW / 4 + 255) / 256, 2);
    k_tof16<<<tg, 256, 0, stream>>>(Wl, Wr, WfL, WfR, nW);

    // CSR build (binned two-phase)
    k_zero_int<<<1, 256, 0, stream>>>(gcnt, 256);
    k_binA<<<(E + ACHUNK - 1) / ACHUNK, 256, 0, stream>>>(src, dst, E, gcnt, arena);
    k_scan_bk<<<1, 256, 0, stream>>>(gcnt, nbk, bstart, rowptr, N, E);
    k_binB<<<nbk, 256, 0, stream>>>(arena, gcnt, bstart, N, rowptr, csr_off);

    // embedding -> fp16 x (buffer A)
    k_embed<<<N, 128, 0, stream>>>(nf, W_emb, b_emb, xA, N);

    dim3 lgrid((N + 255) / 256, 2);
    for (int i = 0; i < 4; i++) {
        // ping-pong: even layers read A write B, odd layers read B write A
        const _Float16* xin = (i & 1) ? xB : xA;
        _Float16* xo        = (i & 1) ? xA : xB;
        k_linear_mfma<<<lgrid, 512, 0, stream>>>(xin,
                                                 WfL + (size_t)i * HID * HID, WfR + (size_t)i * HID * HID,
                                                 bl + i * HID, br + i * HID, xlh, xrh, N);
        k_attn<<<(N + 3) / 4, 256, 0, stream>>>(xlh, xrh, rowptr, csr_off,
                                                att + i * HEADS * 32, bias + i * HID,
                                                xin, xo, xout,
                                                i > 0 ? 1 : 0, i < 3 ? 1 : 0, N);
    }

    k_reduce1<<<R1B, 256, 0, stream>>>(xout, N, psum, pmax);
    k_reduce2<<<1, 1024, 0, stream>>>(psum, pmax, R1B, out, 1.0f / N);
}